// Round 12
// baseline (154.739 us; speedup 1.0000x reference)
//
#include <hip/hip_runtime.h>
#include <math.h>

#define IN_CH 128
#define OUT_CH 64
#define NEG_SLOPE 0.2f
#define CAP 32   // slots/node (ushort), 64B line = exactly one node's row.

// ---------- bf16 helpers ----------
__device__ __forceinline__ unsigned short f2bf(float f) {
    unsigned u = __float_as_uint(f);
    unsigned r = (u + 0x7FFFu + ((u >> 16) & 1u)) >> 16;   // round-nearest-even
    return (unsigned short)r;
}

// ---------- edge dtype sniff: int64 little-endian => odd int32 words are 0 ----------
__device__ __forceinline__ bool sniff_is64(const void* edges) {
    const unsigned* up = (const unsigned*)edges;
    bool is64 = true;
#pragma unroll
    for (int k = 0; k < 16; k++) is64 = is64 && (up[2 * k + 1] == 0u);
    return is64;
}

// ---------- K1 (fused): bid%16 < 8 -> cs role (bucket = bid%8 ~ home XCD);
//                        bid%16 >= 8 -> mm role.
// cs: chunk of 2048 edges, process only edges with dst%8 == bucket. All writes to
//     a node's slot line then come from ONE XCD -> write-back ~6MB instead of 45.
// mm: h16 = bf16(x@W) + att dots, W in two 16KB LDS halves.
__global__ __launch_bounds__(256) void k_fused(
        const float* __restrict__ x, const float* __restrict__ W,
        const float* __restrict__ att, unsigned short* __restrict__ h16,
        float* __restrict__ asrc, float* __restrict__ adst, int N,
        const void* __restrict__ edges, int* __restrict__ counts,
        unsigned short* __restrict__ slots, int* __restrict__ oflow_cnt,
        int2* __restrict__ oflow, int E, int mmb) {
    __shared__ float Ws[64 * OUT_CH];   // 16 KB (mm role only)
    int t = threadIdx.x;
    int bid = blockIdx.x;
    int g = bid >> 4;
    int k = bid & 15;

    if (k < 8) {
        // ----- cs role: chunk g, bucket k -----
        int bucket = k;
        long base = (long)g * 2048;
        if (base >= E) return;
        bool is64 = sniff_is64(edges);
        if (is64 && !(E & 1)) {
            const long long* p = (const long long*)edges;
#pragma unroll
            for (int it = 0; it < 4; it++) {
                long e = base + (it * 256 + t) * 2;
                if (e + 1 < E) {
                    int4 vd = *(const int4*)&p[E + e];   // dst pair (16B aligned)
                    if ((vd.x & 7) == bucket) {
                        int s = (int)p[e];
                        int r = atomicAdd(counts + vd.x, 1);
                        if (r < CAP) slots[((size_t)vd.x << 5) + r] = (unsigned short)s;
                        else { int q = atomicAdd(oflow_cnt, 1); oflow[q] = make_int2(s, vd.x); }
                    }
                    if ((vd.z & 7) == bucket) {
                        int s = (int)p[e + 1];
                        int r = atomicAdd(counts + vd.z, 1);
                        if (r < CAP) slots[((size_t)vd.z << 5) + r] = (unsigned short)s;
                        else { int q = atomicAdd(oflow_cnt, 1); oflow[q] = make_int2(s, vd.z); }
                    }
                } else if (e < E) {
                    int d = (int)p[E + e];
                    if ((d & 7) == bucket) {
                        int s = (int)p[e];
                        int r = atomicAdd(counts + d, 1);
                        if (r < CAP) slots[((size_t)d << 5) + r] = (unsigned short)s;
                        else { int q = atomicAdd(oflow_cnt, 1); oflow[q] = make_int2(s, d); }
                    }
                }
            }
        } else if (is64) {
            const long long* p = (const long long*)edges;
            for (int it = 0; it < 8; it++) {
                long e = base + it * 256 + t;
                if (e >= E) break;
                int d = (int)p[E + e];
                if ((d & 7) == bucket) {
                    int s = (int)p[e];
                    int r = atomicAdd(counts + d, 1);
                    if (r < CAP) slots[((size_t)d << 5) + r] = (unsigned short)s;
                    else { int q = atomicAdd(oflow_cnt, 1); oflow[q] = make_int2(s, d); }
                }
            }
        } else {
            const int* p = (const int*)edges;
            bool a4 = ((E & 3) == 0);
            if (a4) {
#pragma unroll
                for (int it = 0; it < 2; it++) {
                    long e = base + (it * 256 + t) * 4;
                    if (e + 3 < E) {
                        int4 vd = *(const int4*)&p[E + e];
                        int dd[4] = {vd.x, vd.y, vd.z, vd.w};
#pragma unroll
                        for (int i = 0; i < 4; i++) {
                            if ((dd[i] & 7) == bucket) {
                                int s = p[e + i];
                                int r = atomicAdd(counts + dd[i], 1);
                                if (r < CAP) slots[((size_t)dd[i] << 5) + r] = (unsigned short)s;
                                else { int q = atomicAdd(oflow_cnt, 1); oflow[q] = make_int2(s, dd[i]); }
                            }
                        }
                    } else {
                        for (long e2 = e; e2 < E && e2 < e + 4; e2++) {
                            int d = p[E + e2];
                            if ((d & 7) == bucket) {
                                int s = p[e2];
                                int r = atomicAdd(counts + d, 1);
                                if (r < CAP) slots[((size_t)d << 5) + r] = (unsigned short)s;
                                else { int q = atomicAdd(oflow_cnt, 1); oflow[q] = make_int2(s, d); }
                            }
                        }
                    }
                }
            } else {
                for (int it = 0; it < 8; it++) {
                    long e = base + it * 256 + t;
                    if (e >= E) break;
                    int d = p[E + e];
                    if ((d & 7) == bucket) {
                        int s = p[e];
                        int r = atomicAdd(counts + d, 1);
                        if (r < CAP) slots[((size_t)d << 5) + r] = (unsigned short)s;
                        else { int q = atomicAdd(oflow_cnt, 1); oflow[q] = make_int2(s, d); }
                    }
                }
            }
        }
        return;
    }

    // ----- mm role -----
    int id = g * 8 + (k - 8);
    if (id >= mmb) return;
    int cg = t & 15, gg = t >> 4;
    float4 att_d = *(const float4*)&att[cg * 4];        // dst half: att[0:64]
    float4 att_s = *(const float4*)&att[64 + cg * 4];   // src half: att[64:128]

    int n0 = id * 64 + gg * 4;
    int nn[4];
#pragma unroll
    for (int m = 0; m < 4; m++) nn[m] = min(n0 + m, N - 1);

    float4 acc[4];
#pragma unroll
    for (int m = 0; m < 4; m++) acc[m] = make_float4(0.f, 0.f, 0.f, 0.f);

    const int HALF = 64 * OUT_CH;   // 16 KB
#pragma unroll
    for (int h = 0; h < 2; h++) {
        if (h) __syncthreads();
        for (int i = t * 4; i < HALF; i += 256 * 4)
            *(float4*)&Ws[i] = *(const float4*)&W[h * HALF + i];
        __syncthreads();
#pragma unroll 2
        for (int k4 = 0; k4 < 16; k4++) {
            float4 xv[4];
#pragma unroll
            for (int m = 0; m < 4; m++)
                xv[m] = *(const float4*)&x[(size_t)nn[m] * IN_CH + h * 64 + k4 * 4];
            float4 wv[4];
#pragma unroll
            for (int j = 0; j < 4; j++)
                wv[j] = *(const float4*)&Ws[(k4 * 4 + j) * OUT_CH + cg * 4];
#pragma unroll
            for (int m = 0; m < 4; m++) {
                acc[m].x = fmaf(xv[m].x, wv[0].x, acc[m].x);
                acc[m].y = fmaf(xv[m].x, wv[0].y, acc[m].y);
                acc[m].z = fmaf(xv[m].x, wv[0].z, acc[m].z);
                acc[m].w = fmaf(xv[m].x, wv[0].w, acc[m].w);
                acc[m].x = fmaf(xv[m].y, wv[1].x, acc[m].x);
                acc[m].y = fmaf(xv[m].y, wv[1].y, acc[m].y);
                acc[m].z = fmaf(xv[m].y, wv[1].z, acc[m].z);
                acc[m].w = fmaf(xv[m].y, wv[1].w, acc[m].w);
                acc[m].x = fmaf(xv[m].z, wv[2].x, acc[m].x);
                acc[m].y = fmaf(xv[m].z, wv[2].y, acc[m].y);
                acc[m].z = fmaf(xv[m].z, wv[2].z, acc[m].z);
                acc[m].w = fmaf(xv[m].z, wv[2].w, acc[m].w);
                acc[m].x = fmaf(xv[m].w, wv[3].x, acc[m].x);
                acc[m].y = fmaf(xv[m].w, wv[3].y, acc[m].y);
                acc[m].z = fmaf(xv[m].w, wv[3].z, acc[m].z);
                acc[m].w = fmaf(xv[m].w, wv[3].w, acc[m].w);
            }
        }
    }

#pragma unroll
    for (int m = 0; m < 4; m++) {
        int node = n0 + m;
        if (node < N) {
            ushort4 hv;
            hv.x = f2bf(acc[m].x);
            hv.y = f2bf(acc[m].y);
            hv.z = f2bf(acc[m].z);
            hv.w = f2bf(acc[m].w);
            *(ushort4*)&h16[(size_t)node * OUT_CH + cg * 4] = hv;
        }
        float pd = acc[m].x * att_d.x + acc[m].y * att_d.y +
                   acc[m].z * att_d.z + acc[m].w * att_d.w;
        float ps = acc[m].x * att_s.x + acc[m].y * att_s.y +
                   acc[m].z * att_s.z + acc[m].w * att_s.w;
#pragma unroll
        for (int msk = 1; msk < 16; msk <<= 1) {
            pd += __shfl_xor(pd, msk, 64);
            ps += __shfl_xor(ps, msk, 64);
        }
        if (cg == 0 && node < N) { adst[node] = pd; asrc[node] = ps; }
    }
}

// ---------- K2: per-node slot-gather softmax-aggregate + bias + L2 normalize ----------
// XCD-aligned: block bid handles nodes with node%8 == bid%8, so slot rows are read
// from the L2 that wrote them. 1 wave/node, 2 ch/lane, half-waves cover 2 rows/load.
__global__ __launch_bounds__(256) void k_agg(const unsigned short* __restrict__ h16,
                                             const unsigned short* __restrict__ slots,
                                             const int* __restrict__ counts,
                                             const int* __restrict__ oflow_cnt,
                                             const int2* __restrict__ oflow,
                                             const float* __restrict__ asrc,
                                             const float* __restrict__ adst,
                                             const float* __restrict__ bias,
                                             float* __restrict__ out, int N) {
    __shared__ float2 stage[4][64];   // wave-private
    int lane = threadIdx.x & 63;
    int wid = threadIdx.x >> 6;
    int b = blockIdx.x & 7;
    int kk = blockIdx.x >> 3;
    int node = b + 8 * (kk * 4 + wid);
    if (node >= N) return;
    int half = lane >> 5;
    int ch2 = (lane & 31) * 2;

    float aD = adst[node];
    // analytic self loop (h row counted in half 0 only)
    float a = aD + asrc[node];
    a = a > 0.f ? a : NEG_SLOPE * a;
    float w_self = __expf(a);
    unsigned hv = *(const unsigned*)&h16[(size_t)node * OUT_CH + ch2];
    float wse = half ? 0.f : w_self;
    float accx = wse * __uint_as_float(hv << 16);
    float accy = wse * __uint_as_float(hv & 0xFFFF0000u);

    int c = counts[node];           // true degree (may exceed CAP)
    int cs = min(c, CAP);
    int sv = 0;
    float wv = 0.f;
    if (lane < cs) {
        sv = (int)slots[((size_t)node << 5) + lane];   // 64B row, local-L2-hot
        float av = aD + asrc[sv];
        av = av > 0.f ? av : NEG_SLOPE * av;
        wv = __expf(av);
    }
    float esum_lane = wv;
    stage[wid][lane] = make_float2(__int_as_float(sv), wv);

    for (int j = 0; j < cs; j += 16) {
#pragma unroll
        for (int k = 0; k < 8; k++) {
            float2 p = stage[wid][j + 2 * k + half];   // 2-addr broadcast, free
            int s = __float_as_int(p.x);
            unsigned v = *(const unsigned*)&h16[((size_t)s << 6) + ch2];
            accx = fmaf(p.y, __uint_as_float(v << 16), accx);
            accy = fmaf(p.y, __uint_as_float(v & 0xFFFF0000u), accy);
        }
    }
    // combine half-waves
    accx += __shfl_xor(accx, 32, 64);
    accy += __shfl_xor(accy, 32, 64);
#pragma unroll
    for (int m = 32; m >= 1; m >>= 1) esum_lane += __shfl_xor(esum_lane, m, 64);
    float esum = esum_lane + w_self;

    // cold overflow path (correct for any input)
    int oc = *oflow_cnt;
    if (oc > 0) {
        for (int i = 0; i < oc; i++) {
            int2 e = oflow[i];
            if (e.y == node) {
                float av = aD + asrc[e.x];
                av = av > 0.f ? av : NEG_SLOPE * av;
                float w = __expf(av);
                esum += w;
                unsigned v = *(const unsigned*)&h16[((size_t)e.x << 6) + ch2];
                accx = fmaf(w, __uint_as_float(v << 16), accx);
                accy = fmaf(w, __uint_as_float(v & 0xFFFF0000u), accy);
            }
        }
    }

    float inv = 1.f / (esum + 1e-16f);
    float2 bv = *(const float2*)&bias[ch2];
    float vx = accx * inv + bv.x;
    float vy = accy * inv + bv.y;
    float ss = vx * vx + vy * vy;
#pragma unroll
    for (int m = 16; m >= 1; m >>= 1) ss += __shfl_xor(ss, m, 64);   // within half
    float rinv = 1.f / fmaxf(sqrtf(ss), 1e-12f);
    if (!half)
        *(float2*)&out[(size_t)node * OUT_CH + ch2] = make_float2(vx * rinv, vy * rinv);
}

extern "C" void kernel_launch(void* const* d_in, const int* in_sizes, int n_in,
                              void* d_out, int out_size, void* d_ws, size_t ws_size,
                              hipStream_t stream) {
    const float* x    = (const float*)d_in[0];
    const void*  edges = d_in[1];
    const float* W    = (const float*)d_in[2];
    const float* att  = (const float*)d_in[3];
    const float* bias = (const float*)d_in[4];
    float* out = (float*)d_out;

    const int N = in_sizes[0] / IN_CH;
    const int E = in_sizes[1] / 2;
    const int MMB = (N + 63) / 64;              // mm role blocks needed
    const int CH  = (E + 2047) / 2048;          // cs chunks
    const int GM  = (MMB + 7) / 8;              // groups needed by mm
    const int G   = (CH > GM ? CH : GM);        // groups
    const int GRID = G * 16;

    char* ws = (char*)d_ws;
    size_t off = 0;
    auto alloc = [&](size_t bytes) -> void* {
        void* p = ws + off;
        off += bytes;
        off = (off + 255) & ~(size_t)255;
        return p;
    };
    int*            counts    = (int*)alloc((size_t)(N + 64) * 4);   // +oflow_cnt
    unsigned short* slots     = (unsigned short*)alloc((size_t)N * CAP * 2);
    int2*           oflow     = (int2*)alloc((size_t)E * 8);
    unsigned short* h16       = (unsigned short*)alloc((size_t)N * OUT_CH * 2);
    float*          asrc      = (float*)alloc((size_t)N * 4);
    float*          adst      = (float*)alloc((size_t)N * 4);
    int*            oflow_cnt = counts + N;

    hipMemsetAsync(counts, 0, (size_t)(N + 64) * 4, stream);
    k_fused<<<GRID, 256, 0, stream>>>(x, W, att, h16, asrc, adst, N,
                                      edges, counts, slots, oflow_cnt,
                                      oflow, E, MMB);
    const int NP  = (N + 7) / 8;                // nodes per bucket (max)
    const int AGB = 8 * ((NP + 3) / 4);
    k_agg<<<AGB, 256, 0, stream>>>(h16, slots, counts, oflow_cnt, oflow,
                                   asrc, adst, bias, out, N);
}

// Round 13
// 142.801 us; speedup vs baseline: 1.0836x; 1.0836x over previous
//
#include <hip/hip_runtime.h>
#include <math.h>

#define IN_CH 128
#define OUT_CH 64
#define NEG_SLOPE 0.2f
#define CAP 64   // slots per node; mean degree 16, P(deg>64) ~ 1e-16 for uniform dst

// ---------- bf16 helpers ----------
__device__ __forceinline__ unsigned short f2bf(float f) {
    unsigned u = __float_as_uint(f);
    unsigned r = (u + 0x7FFFu + ((u >> 16) & 1u)) >> 16;   // round-nearest-even
    return (unsigned short)r;
}

// ---------- edge dtype sniff: int64 little-endian => odd int32 words are 0 ----------
__device__ __forceinline__ bool sniff_is64(const void* edges) {
    const unsigned* up = (const unsigned*)edges;
    bool is64 = true;
#pragma unroll
    for (int k = 0; k < 16; k++) is64 = is64 && (up[2 * k + 1] == 0u);
    return is64;
}

// ---------- K1 (fused, interleaved): even blocks mm, odd blocks count+scatter ----------
// cs path edge reads are NON-TEMPORAL: the streaming edge columns otherwise thrash
// L2 and evict dirty slot lines mid-accumulation (R12 evidence: write-back ~10x the
// 3.2MB payload even with XCD-pure lines). nt keeps L2 for the slot region.
__global__ __launch_bounds__(256) void k_mm_cs(
        const float* __restrict__ x, const float* __restrict__ W,
        const float* __restrict__ att, unsigned short* __restrict__ h16,
        float* __restrict__ asrc, float* __restrict__ adst, int N,
        const void* __restrict__ edges, int* __restrict__ counts,
        int* __restrict__ slots, int* __restrict__ oflow_cnt,
        int2* __restrict__ oflow, int E, int mmb, int csb) {
    __shared__ float Ws[IN_CH * OUT_CH];   // 32 KB (mm role only)
    int t = threadIdx.x;
    int bid = blockIdx.x;
    int lo = min(mmb, csb), M2 = 2 * lo;
    int role, id;   // role 0 = mm, 1 = count+scatter
    if (bid < M2) { role = bid & 1; id = bid >> 1; }
    else          { role = (mmb > csb) ? 0 : 1; id = bid - M2 + lo; }

    if (role == 1) {
        // ----- count+scatter path: 4 edges/thread, single edge pass, nt loads -----
        int e0 = (id * 256 + t) * 4;
        if (e0 >= E) return;
        int s[4], d[4];
        bool full = (e0 + 3 < E);
        if (full) {
            if (sniff_is64(edges)) {
                const long long* p = (const long long*)edges;
#pragma unroll
                for (int i = 0; i < 4; i++) {
                    s[i] = (int)__builtin_nontemporal_load(p + e0 + i);
                    d[i] = (int)__builtin_nontemporal_load(p + (size_t)E + e0 + i);
                }
            } else {
                const int* p = (const int*)edges;
#pragma unroll
                for (int i = 0; i < 4; i++) {
                    s[i] = __builtin_nontemporal_load(p + e0 + i);
                    d[i] = __builtin_nontemporal_load(p + E + e0 + i);
                }
            }
#pragma unroll
            for (int i = 0; i < 4; i++) {
                int r = atomicAdd(counts + d[i], 1);
                if (r < CAP) {
                    slots[((size_t)d[i] << 6) + r] = s[i];
                } else {
                    int p2 = atomicAdd(oflow_cnt, 1);
                    oflow[p2] = make_int2(s[i], d[i]);
                }
            }
        } else {
            bool is64 = sniff_is64(edges);
            for (int i = 0; i < 4; i++) {
                if (e0 + i >= E) break;
                int sv, dv;
                if (is64) {
                    const long long* p = (const long long*)edges;
                    sv = (int)p[e0 + i];
                    dv = (int)p[(size_t)E + e0 + i];
                } else {
                    const int* p = (const int*)edges;
                    sv = p[e0 + i];
                    dv = p[E + e0 + i];
                }
                int r = atomicAdd(counts + dv, 1);
                if (r < CAP) {
                    slots[((size_t)dv << 6) + r] = sv;
                } else {
                    int p2 = atomicAdd(oflow_cnt, 1);
                    oflow[p2] = make_int2(sv, dv);
                }
            }
        }
        return;
    }

    // ----- mm path -----
    for (int i = t * 4; i < IN_CH * OUT_CH; i += 256 * 4)
        *(float4*)&Ws[i] = *(const float4*)&W[i];
    int cg = t & 15, g = t >> 4;
    float4 att_d = *(const float4*)&att[cg * 4];        // dst half: att[0:64]
    float4 att_s = *(const float4*)&att[64 + cg * 4];   // src half: att[64:128]
    __syncthreads();

    int n0 = id * 64 + g * 4;
    int nn[4];
#pragma unroll
    for (int m = 0; m < 4; m++) nn[m] = min(n0 + m, N - 1);

    float4 acc[4];
#pragma unroll
    for (int m = 0; m < 4; m++) acc[m] = make_float4(0.f, 0.f, 0.f, 0.f);

#pragma unroll 2
    for (int k4 = 0; k4 < IN_CH / 4; k4++) {
        float4 xv[4];
#pragma unroll
        for (int m = 0; m < 4; m++)
            xv[m] = *(const float4*)&x[(size_t)nn[m] * IN_CH + k4 * 4];
        float4 wv[4];
#pragma unroll
        for (int j = 0; j < 4; j++)
            wv[j] = *(const float4*)&Ws[(k4 * 4 + j) * OUT_CH + cg * 4];
#pragma unroll
        for (int m = 0; m < 4; m++) {
            acc[m].x = fmaf(xv[m].x, wv[0].x, acc[m].x);
            acc[m].y = fmaf(xv[m].x, wv[0].y, acc[m].y);
            acc[m].z = fmaf(xv[m].x, wv[0].z, acc[m].z);
            acc[m].w = fmaf(xv[m].x, wv[0].w, acc[m].w);
            acc[m].x = fmaf(xv[m].y, wv[1].x, acc[m].x);
            acc[m].y = fmaf(xv[m].y, wv[1].y, acc[m].y);
            acc[m].z = fmaf(xv[m].y, wv[1].z, acc[m].z);
            acc[m].w = fmaf(xv[m].y, wv[1].w, acc[m].w);
            acc[m].x = fmaf(xv[m].z, wv[2].x, acc[m].x);
            acc[m].y = fmaf(xv[m].z, wv[2].y, acc[m].y);
            acc[m].z = fmaf(xv[m].z, wv[2].z, acc[m].z);
            acc[m].w = fmaf(xv[m].z, wv[2].w, acc[m].w);
            acc[m].x = fmaf(xv[m].w, wv[3].x, acc[m].x);
            acc[m].y = fmaf(xv[m].w, wv[3].y, acc[m].y);
            acc[m].z = fmaf(xv[m].w, wv[3].z, acc[m].z);
            acc[m].w = fmaf(xv[m].w, wv[3].w, acc[m].w);
        }
    }

#pragma unroll
    for (int m = 0; m < 4; m++) {
        int node = n0 + m;
        if (node < N) {
            ushort4 hv;
            hv.x = f2bf(acc[m].x);
            hv.y = f2bf(acc[m].y);
            hv.z = f2bf(acc[m].z);
            hv.w = f2bf(acc[m].w);
            *(ushort4*)&h16[(size_t)node * OUT_CH + cg * 4] = hv;
        }
        float pd = acc[m].x * att_d.x + acc[m].y * att_d.y +
                   acc[m].z * att_d.z + acc[m].w * att_d.w;
        float ps = acc[m].x * att_s.x + acc[m].y * att_s.y +
                   acc[m].z * att_s.z + acc[m].w * att_s.w;
#pragma unroll
        for (int msk = 1; msk < 16; msk <<= 1) {
            pd += __shfl_xor(pd, msk, 64);
            ps += __shfl_xor(ps, msk, 64);
        }
        if (cg == 0 && node < N) { adst[node] = pd; asrc[node] = ps; }
    }
}

// ---------- K2: per-node slot-gather softmax-aggregate + bias + L2 normalize ----------
// 1 wave/node, 2 channels/lane (ushort2), half-waves cover 2 src rows per load.
__global__ __launch_bounds__(256) void k_agg(const unsigned short* __restrict__ h16,
                                             const int* __restrict__ slots,
                                             const int* __restrict__ counts,
                                             const int* __restrict__ oflow_cnt,
                                             const int2* __restrict__ oflow,
                                             const float* __restrict__ asrc,
                                             const float* __restrict__ adst,
                                             const float* __restrict__ bias,
                                             float* __restrict__ out, int N) {
    __shared__ float2 stage[4][64];   // wave-private
    int lane = threadIdx.x & 63;
    int wid = threadIdx.x >> 6;
    int node = blockIdx.x * 4 + wid;
    if (node >= N) return;
    int half = lane >> 5;
    int ch2 = (lane & 31) * 2;

    float aD = adst[node];
    // analytic self loop (h row counted in half 0 only)
    float a = aD + asrc[node];
    a = a > 0.f ? a : NEG_SLOPE * a;
    float w_self = __expf(a);
    unsigned hv = *(const unsigned*)&h16[(size_t)node * OUT_CH + ch2];
    float wse = half ? 0.f : w_self;
    float accx = wse * __uint_as_float(hv << 16);
    float accy = wse * __uint_as_float(hv & 0xFFFF0000u);

    int c = counts[node];           // true degree (may exceed CAP)
    int cs = min(c, CAP);
    int sv = 0;
    float wv = 0.f;
    if (lane < cs) {
        sv = slots[((size_t)node << 6) + lane];   // coalesced 256B
        float av = aD + asrc[sv];                 // parallel gather (L2-hot)
        av = av > 0.f ? av : NEG_SLOPE * av;
        wv = __expf(av);                          // once per edge
    }
    float esum_lane = wv;
    stage[wid][lane] = make_float2(__int_as_float(sv), wv);

    for (int j = 0; j < cs; j += 16) {
#pragma unroll
        for (int k = 0; k < 8; k++) {
            float2 p = stage[wid][j + 2 * k + half];   // 2-addr broadcast, free
            int s = __float_as_int(p.x);
            unsigned v = *(const unsigned*)&h16[((size_t)s << 6) + ch2];
            accx = fmaf(p.y, __uint_as_float(v << 16), accx);
            accy = fmaf(p.y, __uint_as_float(v & 0xFFFF0000u), accy);
        }
    }
    // combine half-waves (even rows in lanes 0-31, odd rows in 32-63)
    accx += __shfl_xor(accx, 32, 64);
    accy += __shfl_xor(accy, 32, 64);
#pragma unroll
    for (int m = 32; m >= 1; m >>= 1) esum_lane += __shfl_xor(esum_lane, m, 64);
    float esum = esum_lane + w_self;

    // cold overflow path (oc == 0 for this input; correct if not)
    int oc = *oflow_cnt;
    if (oc > 0) {
        for (int i = 0; i < oc; i++) {
            int2 e = oflow[i];
            if (e.y == node) {
                float av = aD + asrc[e.x];
                av = av > 0.f ? av : NEG_SLOPE * av;
                float w = __expf(av);
                esum += w;
                unsigned v = *(const unsigned*)&h16[((size_t)e.x << 6) + ch2];
                accx = fmaf(w, __uint_as_float(v << 16), accx);
                accy = fmaf(w, __uint_as_float(v & 0xFFFF0000u), accy);
            }
        }
    }

    float inv = 1.f / (esum + 1e-16f);
    float2 bv = *(const float2*)&bias[ch2];
    float vx = accx * inv + bv.x;
    float vy = accy * inv + bv.y;
    float ss = vx * vx + vy * vy;
#pragma unroll
    for (int m = 16; m >= 1; m >>= 1) ss += __shfl_xor(ss, m, 64);   // within half
    float rinv = 1.f / fmaxf(sqrtf(ss), 1e-12f);
    if (!half)
        *(float2*)&out[(size_t)node * OUT_CH + ch2] = make_float2(vx * rinv, vy * rinv);
}

extern "C" void kernel_launch(void* const* d_in, const int* in_sizes, int n_in,
                              void* d_out, int out_size, void* d_ws, size_t ws_size,
                              hipStream_t stream) {
    const float* x    = (const float*)d_in[0];
    const void*  edges = d_in[1];
    const float* W    = (const float*)d_in[2];
    const float* att  = (const float*)d_in[3];
    const float* bias = (const float*)d_in[4];
    float* out = (float*)d_out;

    const int N = in_sizes[0] / IN_CH;
    const int E = in_sizes[1] / 2;
    const int MMB = (N + 63) / 64;             // mm blocks
    const int CSB = (E + 1023) / 1024;         // count+scatter blocks (4 edges/thread)

    char* ws = (char*)d_ws;
    size_t off = 0;
    auto alloc = [&](size_t bytes) -> void* {
        void* p = ws + off;
        off += bytes;
        off = (off + 255) & ~(size_t)255;
        return p;
    };
    int*            counts   = (int*)alloc((size_t)(N + 64) * 4);  // +oflow_cnt tail
    int*            slots    = (int*)alloc((size_t)N * CAP * 4);   // 12.8 MB
    int2*           oflow    = (int2*)alloc((size_t)E * 8);        // never used in practice
    unsigned short* h16      = (unsigned short*)alloc((size_t)N * OUT_CH * 2);
    float*          asrc     = (float*)alloc((size_t)N * 4);
    float*          adst     = (float*)alloc((size_t)N * 4);
    int*            oflow_cnt = counts + N;

    hipMemsetAsync(counts, 0, (size_t)(N + 64) * 4, stream);
    k_mm_cs<<<MMB + CSB, 256, 0, stream>>>(x, W, att, h16, asrc, adst, N,
                                           edges, counts, slots, oflow_cnt,
                                           oflow, E, MMB, CSB);
    k_agg<<<(N + 3) / 4, 256, 0, stream>>>(h16, slots, counts, oflow_cnt, oflow,
                                           asrc, adst, bias, out, N);
}